// Round 11
// baseline (731.111 us; speedup 1.0000x reference)
//
#include <hip/hip_runtime.h>
#include <hip/hip_fp16.h>
#include <cstddef>

// StackLSTM: T=64, B=128, H=256, L=2.  ops∈{0,1} => stack never pops:
// top-of-stack = h(last push step), maintained by gated update.
//
// Round-11: r10 pipeline (L1(t)+L0(t+1) per iter, ONE exchange round/step)
// + blockIdx bit-swizzle giving BOTH: (a) exchange-group members on one XCD
// (stride-8 blockIdx), (b) co-resident WGs from 4 different batch groups
// (blockIdx bits 8-9 feed bg). r10's cross-XCD exchange doubled round
// latency; this restores r9's locality while keeping 65 rounds.
#define TT 64
#define BB 128
#define HH 256
#define G4 1024
#define BLK 256
#define NBG 32
#define NHG 32

// ws float-slot offsets
#define OFF_XG     0u          // [64 t][32 hg][128 b][32 lc] fp32 = 8,388,608
#define OFF_WTIH0  8388608u    // [256][1024] fp32 W_ih[0]^T (for xg) = 262,144
#define OFF_HX0    8650752u    // u64 [2 par][32 bg][4 b][128 k2] = 65,536 floats
#define OFF_HX1    8716288u    // same
// total 8,781,824 floats = 35.1 MB

__device__ __forceinline__ float sigf(float x) { return 1.0f / (1.0f + expf(-x)); }

typedef _Float16 h2v __attribute__((ext_vector_type(2)));

__device__ __forceinline__ float dot2acc(unsigned w, unsigned h, float acc) {
#if __has_builtin(__builtin_amdgcn_fdot2)
  return __builtin_amdgcn_fdot2(__builtin_bit_cast(h2v, w),
                                __builtin_bit_cast(h2v, h), acc, false);
#else
  __half2 wv = *(__half2*)&w, hv = *(__half2*)&h;
  float2 wf = __half22float2(wv), hf = __half22float2(hv);
  return fmaf(wf.x, hf.x, fmaf(wf.y, hf.y, acc));
#endif
}

__device__ __forceinline__ unsigned packh2(float e, float o) {
  return (unsigned)__half_as_ushort(__float2half(e)) |
         ((unsigned)__half_as_ushort(__float2half(o)) << 16);
}

// ---------------------------------------------------------------------------
// transpose W_ih[0] [1024][256] -> [256][1024] fp32 (for xg_kernel)
// ---------------------------------------------------------------------------
__global__ void transpose1(const float* __restrict__ W_ih, float* __restrict__ ws) {
  __shared__ float tile[32][33];
  float* dst = ws + OFF_WTIH0;
  const int g0 = blockIdx.x * 32, k0 = blockIdx.y * 32;
  const int tx = threadIdx.x, ty = threadIdx.y;
#pragma unroll
  for (int i = 0; i < 32; i += 8)
    tile[ty + i][tx] = W_ih[(size_t)(g0 + ty + i) * HH + k0 + tx];
  __syncthreads();
#pragma unroll
  for (int i = 0; i < 32; i += 8)
    dst[(size_t)(k0 + ty + i) * G4 + g0 + tx] = tile[tx][ty + i];
}

// ---------------------------------------------------------------------------
// Xg[t][hg][b][lc] = b_ih0[g] + x[t,b,:] @ W_ih0[g,:]   (fp32, exact)
// hg = (g>>3)&31, lc = (g>>8)*8 + (g&7)
// ---------------------------------------------------------------------------
__global__ void xg_kernel(const float* __restrict__ x,
                          const float* __restrict__ b_ih,
                          float* __restrict__ ws) {
  const float* __restrict__ WTih0 = ws + OFF_WTIH0;
  float* __restrict__ Xg = ws + OFF_XG;
  const int r0 = blockIdx.x * 16;
  const int g = blockIdx.y * 256 + threadIdx.x;
  __shared__ float xs[16][HH];
  for (int i = threadIdx.x; i < 16 * HH; i += 256)
    xs[i >> 8][i & 255] = x[(size_t)(r0 + (i >> 8)) * HH + (i & 255)];
  __syncthreads();
  float acc[16];
  const float bias = b_ih[g];
#pragma unroll
  for (int r = 0; r < 16; ++r) acc[r] = bias;
  for (int k = 0; k < HH; ++k) {
    const float w = WTih0[(size_t)k * G4 + g];
#pragma unroll
    for (int r = 0; r < 16; ++r) acc[r] = fmaf(xs[r][k], w, acc[r]);
  }
  const int hg = (g >> 3) & 31;
  const int lc = ((g >> 8) << 3) | (g & 7);
#pragma unroll
  for (int r = 0; r < 16; ++r) {
    const int rr = r0 + r;
    const int t = rr >> 7, b = rr & 127;
    Xg[(((size_t)t * NHG + hg) * 128 + b) * 32 + lc] = acc[r];
  }
}

// ---------------------------------------------------------------------------
// Sequential recurrence: pipelined tagged dataflow, 48 weight regs/thread.
// Thread (cc = tid>>3, kq = tid&7): col cc, k2 slice
// {s*32 + kq*4 + i : s in 0..3, i in 0..3} (bank-conflict-free b128 reads).
// blockIdx swizzle: bg from bits {0-2, 8-9}, hg from bits {3-7} =>
// exchange-group members stride 8 (one XCD), co-residents differ in bg.
// ---------------------------------------------------------------------------
__global__ void __launch_bounds__(BLK, 4)
seq11(const float* __restrict__ W_ih,
      const float* __restrict__ W_hh,
      const float* __restrict__ b_ih,
      const float* __restrict__ b_hh,
      const int* __restrict__ ops,
      float* __restrict__ ws,
      float* __restrict__ out) {
  const int blk = blockIdx.x;
  const int bg = (blk & 7) | (((blk >> 8) & 3) << 3);  // batch group (4 b)
  const int hg = (blk >> 3) & 31;                      // h-col group
  const int tid = threadIdx.x;
  const int kq = tid & 7;
  const int cc = tid >> 3;            // 0..31: local gate col

  __shared__ unsigned hp0[512];       // [4 b][128 k2] f16-pair gated h0
  __shared__ unsigned hp1[512];
  __shared__ unsigned h0c[512];       // raw h0(t), layer-1 input
  __shared__ float gat0[128];         // gates0(t+1) partial [4 b][32 lc]
  __shared__ float gat1[128];         // gates1(t)   partial
  __shared__ float xgb[128];          // Xg(t+1) [4 b][32 lc]
  __shared__ int opsA[TT * 4];        // [t][b]

  // ---- prologue: weights -> VGPRs (f16 pairs, strided-k layout) ----
  unsigned wr0[16], wr1[16], wr2[16];
  const int g = ((cc >> 3) << 8) + hg * 8 + (cc & 7);
  {
    const float* s0 = W_hh;                       // W_hh[0]
    const float* s1 = W_ih + (size_t)G4 * HH;     // W_ih[1]
    const float* s2 = W_hh + (size_t)G4 * HH;     // W_hh[1]
#pragma unroll
    for (int s = 0; s < 4; ++s)
#pragma unroll
      for (int i = 0; i < 4; ++i) {
        const int k2 = s * 32 + kq * 4 + i;
        const float* p0 = s0 + (size_t)g * HH + 2 * k2;
        const float* p1 = s1 + (size_t)g * HH + 2 * k2;
        const float* p2 = s2 + (size_t)g * HH + 2 * k2;
        wr0[s * 4 + i] = packh2(p0[0], p0[1]);
        wr1[s * 4 + i] = packh2(p1[0], p1[1]);
        wr2[s * 4 + i] = packh2(p2[0], p2[1]);
      }
  }
  const float bias0 = b_hh[g];                     // b_ih0 folded into Xg
  const float bias1 = b_ih[G4 + g] + b_hh[G4 + g];
  for (int i = tid; i < TT * 4; i += BLK)
    opsA[i] = ops[(i >> 2) * BB + bg * 4 + (i & 3)];
  for (int i = tid; i < 512; i += BLK) { hp0[i] = 0u; hp1[i] = 0u; }

  unsigned long long* __restrict__ Hx0 = (unsigned long long*)(ws + OFF_HX0);
  unsigned long long* __restrict__ Hx1 = (unsigned long long*)(ws + OFF_HX1);
  float cp0 = 0.f;                    // layer-0 cell state (wave0 lanes 0..31)
  float cp1 = 0.f;                    // layer-1 cell state (wave1 lanes 0..31)

  // ---- pipeline prologue: step-0 layer-0 (hp0 = 0 -> dots are zero) ----
  if (kq == 0) {
#pragma unroll
    for (int b = 0; b < 4; ++b) gat0[b * 32 + cc] = bias0;
  }
  if (tid < 128)
    xgb[tid] = ws[OFF_XG + (((size_t)0 * NHG + hg) * 128 + bg * 4 + (tid >> 5)) * 32 +
                  (tid & 31)];
  __syncthreads();
  if (tid < 32) {
    const int b = tid >> 3, r = tid & 7;
    const float* gt = &gat0[b * 32];
    const float* xg = &xgb[b * 32];
    const float ig = gt[r] + xg[r],           fg = gt[8 + r] + xg[8 + r];
    const float gg = gt[16 + r] + xg[16 + r], og = gt[24 + r] + xg[24 + r];
    const float c = sigf(ig) * tanhf(gg) + sigf(fg) * cp0;  // cp0 = 0
    const float h = sigf(og) * tanhf(c);
    if (opsA[b]) cp0 = c;
    const float ho = __shfl_xor(h, 1, 64);
    if (!(r & 1)) {
      const unsigned long long v = 1ull | ((unsigned long long)packh2(h, ho) << 32);
      __hip_atomic_store(Hx0 + ((size_t)0 * NBG + bg) * 512 + b * 128 + hg * 4 + (r >> 1),
                         v, __ATOMIC_RELAXED, __HIP_MEMORY_SCOPE_AGENT);
    }
  }
  // merge h0(0)
#pragma unroll
  for (int i = 0; i < 2; ++i) {
    const int idx = tid + i * 256;
    const int b = idx >> 7, k2 = idx & 127;
    const unsigned long long* s0 = Hx0 + ((size_t)0 * NBG + bg) * 512;
    unsigned long long v;
    int spins = 0;
    for (;;) {
      v = __hip_atomic_load(s0 + idx, __ATOMIC_RELAXED, __HIP_MEMORY_SCOPE_AGENT);
      if ((unsigned)v == 1u) break;
      if (++spins > (1 << 18)) break;  // fail loudly instead of hanging
      __builtin_amdgcn_s_sleep(1);
    }
    const unsigned pay = (unsigned)(v >> 32);
    h0c[b * 128 + k2] = pay;
    if (opsA[b]) hp0[b * 128 + k2] = pay;
  }
  __syncthreads();

  // ---- main loop: iteration t does L1(t) and L0(t+1) ----
  for (int t = 0; t < TT; ++t) {
    const bool last = (t == TT - 1);

    // Xg(t+1) early load
    float xgv = 0.f;
    if (!last && tid < 128)
      xgv = ws[OFF_XG + (((size_t)(t + 1) * NHG + hg) * 128 + bg * 4 + (tid >> 5)) * 32 +
               (tid & 31)];

    // ---- L1(t) dots: wr1 . h0c + wr2 . hp1 ----
    float a1[4];
#pragma unroll
    for (int b = 0; b < 4; ++b) {
      float a = 0.f;
#pragma unroll
      for (int s = 0; s < 4; ++s) {
        const uint4 hc = *(const uint4*)&h0c[b * 128 + s * 32 + kq * 4];
        const uint4 hq = *(const uint4*)&hp1[b * 128 + s * 32 + kq * 4];
        a = dot2acc(wr1[s * 4 + 0], hc.x, a);
        a = dot2acc(wr1[s * 4 + 1], hc.y, a);
        a = dot2acc(wr1[s * 4 + 2], hc.z, a);
        a = dot2acc(wr1[s * 4 + 3], hc.w, a);
        a = dot2acc(wr2[s * 4 + 0], hq.x, a);
        a = dot2acc(wr2[s * 4 + 1], hq.y, a);
        a = dot2acc(wr2[s * 4 + 2], hq.z, a);
        a = dot2acc(wr2[s * 4 + 3], hq.w, a);
      }
      a1[b] = a;
    }
    // ---- L0(t+1) dots: wr0 . hp0 ----
    float a0[4];
#pragma unroll
    for (int b = 0; b < 4; ++b) {
      float a = 0.f;
#pragma unroll
      for (int s = 0; s < 4; ++s) {
        const uint4 hx = *(const uint4*)&hp0[b * 128 + s * 32 + kq * 4];
        a = dot2acc(wr0[s * 4 + 0], hx.x, a);
        a = dot2acc(wr0[s * 4 + 1], hx.y, a);
        a = dot2acc(wr0[s * 4 + 2], hx.z, a);
        a = dot2acc(wr0[s * 4 + 3], hx.w, a);
      }
      a0[b] = a;
    }
#pragma unroll
    for (int m = 1; m <= 4; m <<= 1)
#pragma unroll
      for (int b = 0; b < 4; ++b) {
        a1[b] += __shfl_xor(a1[b], m, 64);
        a0[b] += __shfl_xor(a0[b], m, 64);
      }
    if (kq == 0) {
#pragma unroll
      for (int b = 0; b < 4; ++b) {
        gat1[b * 32 + cc] = a1[b] + bias1;
        gat0[b * 32 + cc] = a0[b] + bias0;
      }
    }
    if (!last && tid < 128) xgb[tid] = xgv;
    __syncthreads();

    // ---- cells: cell0(t+1) on wave0 lanes 0..31; cell1(t) on wave1 ----
    if (tid < 32) {
      if (!last) {
        const int b = tid >> 3, r = tid & 7;
        const float* gt = &gat0[b * 32];
        const float* xg = &xgb[b * 32];
        const float ig = gt[r] + xg[r],           fg = gt[8 + r] + xg[8 + r];
        const float gg = gt[16 + r] + xg[16 + r], og = gt[24 + r] + xg[24 + r];
        const float c = sigf(fg) * cp0 + sigf(ig) * tanhf(gg);
        const float h = sigf(og) * tanhf(c);
        if (opsA[(t + 1) * 4 + b]) cp0 = c;
        const float ho = __shfl_xor(h, 1, 64);
        if (!(r & 1)) {
          const unsigned long long v =
              (unsigned long long)(unsigned)(t + 2) |
              ((unsigned long long)packh2(h, ho) << 32);
          __hip_atomic_store(
              Hx0 + ((size_t)((t + 1) & 1) * NBG + bg) * 512 + b * 128 + hg * 4 + (r >> 1),
              v, __ATOMIC_RELAXED, __HIP_MEMORY_SCOPE_AGENT);
        }
      }
    } else if (tid >= 64 && tid < 96) {
      const int lane = tid - 64;
      const int b = lane >> 3, r = lane & 7;
      const float* gt = &gat1[b * 32];
      const float ig = gt[r],      fg = gt[8 + r];
      const float gg = gt[16 + r], og = gt[24 + r];
      const float c = sigf(fg) * cp1 + sigf(ig) * tanhf(gg);
      const float h = sigf(og) * tanhf(c);
      if (opsA[t * 4 + b]) cp1 = c;
      out[((size_t)t * BB + bg * 4 + b) * HH + hg * 8 + r] = h;
      const float ho = __shfl_xor(h, 1, 64);
      if (!(r & 1)) {
        const unsigned long long v =
            (unsigned long long)(unsigned)(t + 1) |
            ((unsigned long long)packh2(h, ho) << 32);
        __hip_atomic_store(
            Hx1 + ((size_t)(t & 1) * NBG + bg) * 512 + b * 128 + hg * 4 + (r >> 1),
            v, __ATOMIC_RELAXED, __HIP_MEMORY_SCOPE_AGENT);
      }
    }

    // ---- combined merge: poll h1(t) and h0(t+1) ----
#pragma unroll
    for (int i = 0; i < 2; ++i) {
      const int idx = tid + i * 256;
      const int b = idx >> 7, k2 = idx & 127;
      {
        const unsigned long long* s1 = Hx1 + ((size_t)(t & 1) * NBG + bg) * 512;
        const unsigned tagB = (unsigned)(t + 1);
        unsigned long long v;
        int spins = 0;
        for (;;) {
          v = __hip_atomic_load(s1 + idx, __ATOMIC_RELAXED, __HIP_MEMORY_SCOPE_AGENT);
          if ((unsigned)v == tagB) break;
          if (++spins > (1 << 18)) break;
          __builtin_amdgcn_s_sleep(1);
        }
        if (opsA[t * 4 + b]) hp1[b * 128 + k2] = (unsigned)(v >> 32);
      }
      if (!last) {
        const unsigned long long* s0 =
            Hx0 + ((size_t)((t + 1) & 1) * NBG + bg) * 512;
        const unsigned tagA = (unsigned)(t + 2);
        unsigned long long v;
        int spins = 0;
        for (;;) {
          v = __hip_atomic_load(s0 + idx, __ATOMIC_RELAXED, __HIP_MEMORY_SCOPE_AGENT);
          if ((unsigned)v == tagA) break;
          if (++spins > (1 << 18)) break;
          __builtin_amdgcn_s_sleep(1);
        }
        const unsigned pay = (unsigned)(v >> 32);
        h0c[b * 128 + k2] = pay;
        if (opsA[(t + 1) * 4 + b]) hp0[b * 128 + k2] = pay;
      }
    }
    __syncthreads();
  }
}

// ---------------------------------------------------------------------------
extern "C" void kernel_launch(void* const* d_in, const int* in_sizes, int n_in,
                              void* d_out, int out_size, void* d_ws, size_t ws_size,
                              hipStream_t stream) {
  const float* x    = (const float*)d_in[0];
  const int*   ops  = (const int*)d_in[1];
  const float* W_ih = (const float*)d_in[2];
  const float* W_hh = (const float*)d_in[3];
  const float* b_ih = (const float*)d_in[4];
  const float* b_hh = (const float*)d_in[5];
  float* out = (float*)d_out;
  float* ws  = (float*)d_ws;

  transpose1<<<dim3(32, 8), dim3(32, 8), 0, stream>>>(W_ih, ws);
  xg_kernel<<<dim3(512, 4), 256, 0, stream>>>(x, b_ih, ws);
  seq11<<<1024, BLK, 0, stream>>>(W_ih, W_hh, b_ih, b_hh, ops, ws, out);
}

// Round 12
// 641.353 us; speedup vs baseline: 1.1400x; 1.1400x over previous
//
#include <hip/hip_runtime.h>
#include <hip/hip_fp16.h>
#include <cstddef>

// StackLSTM: T=64, B=128, H=256, L=2.  ops∈{0,1} => stack never pops:
// top-of-stack = h(last push step), maintained by gated update.
//
// Round-12: one WG = TWO interleaved independent 4-batch chains (A/B) sharing
// the same register-resident weights; every dataflow poll window is backed by
// the other chain's compute. W_ih0 @ x is folded into the step loop as f16
// dots (wx), deleting the 136-us fp32 GEMM prologue. 256 WGs = (pg 0..15,
// hg 0..15), stride-16 exchange groups (same XCD), tagged relaxed-atomic
// dataflow (r7-proven).
#define TT 64
#define BB 128
#define HH 256
#define G4 1024
#define BLK 256

// ws offsets (float slots)
#define OFF_XP   0u          // uint [8192 rows][128 k2] f16-pairs of x
#define OFF_HX0  1048576u    // u64 [2 par][32 bg][4 b][128 k2] = 65,536 floats
#define OFF_HX1  1114112u    // same
// total 1,179,648 floats = 4.7 MB

__device__ __forceinline__ float sigf(float x) { return 1.0f / (1.0f + expf(-x)); }

typedef _Float16 h2v __attribute__((ext_vector_type(2)));

__device__ __forceinline__ float dot2acc(unsigned w, unsigned h, float acc) {
#if __has_builtin(__builtin_amdgcn_fdot2)
  return __builtin_amdgcn_fdot2(__builtin_bit_cast(h2v, w),
                                __builtin_bit_cast(h2v, h), acc, false);
#else
  __half2 wv = *(__half2*)&w, hv = *(__half2*)&h;
  float2 wf = __half22float2(wv), hf = __half22float2(hv);
  return fmaf(wf.x, hf.x, fmaf(wf.y, hf.y, acc));
#endif
}

__device__ __forceinline__ unsigned packh2(float e, float o) {
  return (unsigned)__half_as_ushort(__float2half(e)) |
         ((unsigned)__half_as_ushort(__float2half(o)) << 16);
}

// ---------------------------------------------------------------------------
// pack x [8192][256] f32 -> [8192][128] f16-pair uints
// ---------------------------------------------------------------------------
__global__ void pack_x(const float* __restrict__ x, float* __restrict__ ws) {
  const int i = blockIdx.x * 256 + threadIdx.x;  // [0, 1048576)
  const float2 v = *(const float2*)(x + 2 * (size_t)i);
  ((unsigned*)(ws + OFF_XP))[i] = packh2(v.x, v.y);
}

// ---------------------------------------------------------------------------
// Sequential recurrence: 2 chains/WG, 128 weight regs/thread, fused x-GEMM.
// Thread (c2 = tid>>3, kq = tid&7): cols {2c2, 2c2+1}, k2 slice
// {s*32 + kq*4 + i} (bank-conflict-free b128 LDS reads).
// ---------------------------------------------------------------------------
__global__ void __launch_bounds__(BLK, 2)
seq12(const float* __restrict__ W_ih,
      const float* __restrict__ W_hh,
      const float* __restrict__ b_ih,
      const float* __restrict__ b_hh,
      const int* __restrict__ ops,
      float* __restrict__ ws,
      float* __restrict__ out) {
  const int pg = blockIdx.x & 15;   // pair group; chains bg = 2pg, 2pg+1
  const int hg = blockIdx.x >> 4;   // 0..15 (members stride 16 -> same XCD)
  const int tid = threadIdx.x;
  const int kq = tid & 7;
  const int c2 = tid >> 3;          // 0..31

  __shared__ unsigned hp0[2][512];  // [chain][4 b][128 k2] gated h0 (f16 pairs)
  __shared__ unsigned hp1[2][512];
  __shared__ unsigned h0c[2][512];  // raw h0(t)
  __shared__ float gat0[2][256];    // [chain][4 b][64 lc]
  __shared__ float gat1[2][256];
  __shared__ int opsA[2][TT * 4];   // [chain][t*4+b]

  // ---- prologue: weights -> VGPRs (f16 pairs, strided-k layout) ----
  unsigned wx[32], wr0[32], wr1[32], wr2[32];
  float bias0[2], bias1[2];
#pragma unroll
  for (int j = 0; j < 2; ++j) {
    const int lc = c2 * 2 + j;
    const int g = ((lc >> 4) << 8) + hg * 16 + (lc & 15);
    const float* px = W_ih + (size_t)g * HH;             // W_ih[0]
    const float* p0 = W_hh + (size_t)g * HH;             // W_hh[0]
    const float* p1 = W_ih + (size_t)(G4 + g) * HH;      // W_ih[1]
    const float* p2 = W_hh + (size_t)(G4 + g) * HH;      // W_hh[1]
#pragma unroll
    for (int s = 0; s < 4; ++s)
#pragma unroll
      for (int i = 0; i < 4; ++i) {
        const int k2 = s * 32 + kq * 4 + i;
        wx [j * 16 + s * 4 + i] = packh2(px[2 * k2], px[2 * k2 + 1]);
        wr0[j * 16 + s * 4 + i] = packh2(p0[2 * k2], p0[2 * k2 + 1]);
        wr1[j * 16 + s * 4 + i] = packh2(p1[2 * k2], p1[2 * k2 + 1]);
        wr2[j * 16 + s * 4 + i] = packh2(p2[2 * k2], p2[2 * k2 + 1]);
      }
    bias0[j] = b_ih[g] + b_hh[g];
    bias1[j] = b_ih[G4 + g] + b_hh[G4 + g];
  }
  for (int i = tid; i < TT * 4; i += BLK) {
    opsA[0][i] = ops[(i >> 2) * BB + pg * 8 + (i & 3)];
    opsA[1][i] = ops[(i >> 2) * BB + pg * 8 + 4 + (i & 3)];
  }
  for (int i = tid; i < 512; i += BLK) {
    hp0[0][i] = 0u; hp0[1][i] = 0u; hp1[0][i] = 0u; hp1[1][i] = 0u;
  }

  const unsigned* __restrict__ XP = (const unsigned*)(ws + OFF_XP);
  unsigned long long* __restrict__ Hx0 = (unsigned long long*)(ws + OFF_HX0);
  unsigned long long* __restrict__ Hx1 = (unsigned long long*)(ws + OFF_HX1);
  float cp0[2] = {0.f, 0.f}, cp1[2] = {0.f, 0.f};   // cell state (tid<64)
  __syncthreads();

  // ---- per-phase helpers ----
  auto dotsL0 = [&](int c, int t) {
    float a[4][2];
#pragma unroll
    for (int b = 0; b < 4; ++b) {
      const unsigned* hb = &hp0[c][b * 128];
      const unsigned* xr = XP + ((size_t)t * BB + pg * 8 + c * 4 + b) * 128;
      float s0 = 0.f, s1 = 0.f;
#pragma unroll
      for (int s = 0; s < 4; ++s) {
        const uint4 hx = *(const uint4*)&hb[s * 32 + kq * 4];
        const uint4 xv = *(const uint4*)&xr[s * 32 + kq * 4];
        s0 = dot2acc(wr0[s * 4 + 0], hx.x, s0); s0 = dot2acc(wr0[s * 4 + 1], hx.y, s0);
        s0 = dot2acc(wr0[s * 4 + 2], hx.z, s0); s0 = dot2acc(wr0[s * 4 + 3], hx.w, s0);
        s0 = dot2acc(wx [s * 4 + 0], xv.x, s0); s0 = dot2acc(wx [s * 4 + 1], xv.y, s0);
        s0 = dot2acc(wx [s * 4 + 2], xv.z, s0); s0 = dot2acc(wx [s * 4 + 3], xv.w, s0);
        s1 = dot2acc(wr0[16 + s * 4 + 0], hx.x, s1); s1 = dot2acc(wr0[16 + s * 4 + 1], hx.y, s1);
        s1 = dot2acc(wr0[16 + s * 4 + 2], hx.z, s1); s1 = dot2acc(wr0[16 + s * 4 + 3], hx.w, s1);
        s1 = dot2acc(wx [16 + s * 4 + 0], xv.x, s1); s1 = dot2acc(wx [16 + s * 4 + 1], xv.y, s1);
        s1 = dot2acc(wx [16 + s * 4 + 2], xv.z, s1); s1 = dot2acc(wx [16 + s * 4 + 3], xv.w, s1);
      }
      a[b][0] = s0; a[b][1] = s1;
    }
#pragma unroll
    for (int m = 1; m <= 4; m <<= 1)
#pragma unroll
      for (int b = 0; b < 4; ++b) {
        a[b][0] += __shfl_xor(a[b][0], m, 64);
        a[b][1] += __shfl_xor(a[b][1], m, 64);
      }
    if (kq == 0) {
#pragma unroll
      for (int b = 0; b < 4; ++b)
        *(float2*)&gat0[c][b * 64 + c2 * 2] =
            make_float2(a[b][0] + bias0[0], a[b][1] + bias0[1]);
    }
  };

  auto dotsL1 = [&](int c) {
    float a[4][2];
#pragma unroll
    for (int b = 0; b < 4; ++b) {
      const unsigned* hc = &h0c[c][b * 128];
      const unsigned* hq = &hp1[c][b * 128];
      float s0 = 0.f, s1 = 0.f;
#pragma unroll
      for (int s = 0; s < 4; ++s) {
        const uint4 cv = *(const uint4*)&hc[s * 32 + kq * 4];
        const uint4 qv = *(const uint4*)&hq[s * 32 + kq * 4];
        s0 = dot2acc(wr1[s * 4 + 0], cv.x, s0); s0 = dot2acc(wr1[s * 4 + 1], cv.y, s0);
        s0 = dot2acc(wr1[s * 4 + 2], cv.z, s0); s0 = dot2acc(wr1[s * 4 + 3], cv.w, s0);
        s0 = dot2acc(wr2[s * 4 + 0], qv.x, s0); s0 = dot2acc(wr2[s * 4 + 1], qv.y, s0);
        s0 = dot2acc(wr2[s * 4 + 2], qv.z, s0); s0 = dot2acc(wr2[s * 4 + 3], qv.w, s0);
        s1 = dot2acc(wr1[16 + s * 4 + 0], cv.x, s1); s1 = dot2acc(wr1[16 + s * 4 + 1], cv.y, s1);
        s1 = dot2acc(wr1[16 + s * 4 + 2], cv.z, s1); s1 = dot2acc(wr1[16 + s * 4 + 3], cv.w, s1);
        s1 = dot2acc(wr2[16 + s * 4 + 0], qv.x, s1); s1 = dot2acc(wr2[16 + s * 4 + 1], qv.y, s1);
        s1 = dot2acc(wr2[16 + s * 4 + 2], qv.z, s1); s1 = dot2acc(wr2[16 + s * 4 + 3], qv.w, s1);
      }
      a[b][0] = s0; a[b][1] = s1;
    }
#pragma unroll
    for (int m = 1; m <= 4; m <<= 1)
#pragma unroll
      for (int b = 0; b < 4; ++b) {
        a[b][0] += __shfl_xor(a[b][0], m, 64);
        a[b][1] += __shfl_xor(a[b][1], m, 64);
      }
    if (kq == 0) {
#pragma unroll
      for (int b = 0; b < 4; ++b)
        *(float2*)&gat1[c][b * 64 + c2 * 2] =
            make_float2(a[b][0] + bias1[0], a[b][1] + bias1[1]);
    }
  };

  auto cell0 = [&](int c, int t) {
    if (tid < 64) {
      const int b = tid >> 4, r = tid & 15;
      const float* gt = &gat0[c][b * 64];
      const float ig = gt[r],      fg = gt[16 + r];
      const float gg = gt[32 + r], og = gt[48 + r];
      const float cn = sigf(fg) * cp0[c] + sigf(ig) * tanhf(gg);
      const float h = sigf(og) * tanhf(cn);
      if (opsA[c][t * 4 + b]) cp0[c] = cn;
      const float ho = __shfl_xor(h, 1, 64);
      if (!(r & 1)) {
        const unsigned long long v =
            (unsigned long long)(unsigned)(t + 1) |
            ((unsigned long long)packh2(h, ho) << 32);
        __hip_atomic_store(
            Hx0 + ((size_t)(t & 1) * 32 + pg * 2 + c) * 512 + b * 128 + hg * 8 + (r >> 1),
            v, __ATOMIC_RELAXED, __HIP_MEMORY_SCOPE_AGENT);
      }
    }
  };

  auto cell1 = [&](int c, int t) {
    if (tid < 64) {
      const int b = tid >> 4, r = tid & 15;
      const float* gt = &gat1[c][b * 64];
      const float ig = gt[r],      fg = gt[16 + r];
      const float gg = gt[32 + r], og = gt[48 + r];
      const float cn = sigf(fg) * cp1[c] + sigf(ig) * tanhf(gg);
      const float h = sigf(og) * tanhf(cn);
      if (opsA[c][t * 4 + b]) cp1[c] = cn;
      out[((size_t)t * BB + pg * 8 + c * 4 + b) * HH + hg * 16 + r] = h;
      const float ho = __shfl_xor(h, 1, 64);
      if (!(r & 1)) {
        const unsigned long long v =
            (unsigned long long)(unsigned)(t + 1) |
            ((unsigned long long)packh2(h, ho) << 32);
        __hip_atomic_store(
            Hx1 + ((size_t)(t & 1) * 32 + pg * 2 + c) * 512 + b * 128 + hg * 8 + (r >> 1),
            v, __ATOMIC_RELAXED, __HIP_MEMORY_SCOPE_AGENT);
      }
    }
  };

  auto mergeC = [&](int c, int t) {
#pragma unroll
    for (int i = 0; i < 2; ++i) {
      const int idx = tid + i * 256;
      const int b = idx >> 7, k2 = idx & 127;
      if (t > 0) {  // h1(t-1), published with parity (t-1)&1
        const unsigned long long* s1 =
            Hx1 + ((size_t)((t & 1) ^ 1) * 32 + pg * 2 + c) * 512;
        unsigned long long v;
        int sp = 0;
        for (;;) {
          v = __hip_atomic_load(s1 + idx, __ATOMIC_RELAXED, __HIP_MEMORY_SCOPE_AGENT);
          if ((unsigned)v == (unsigned)t) break;
          if (++sp > (1 << 18)) break;  // fail loudly instead of hanging
          __builtin_amdgcn_s_sleep(1);
        }
        if (opsA[c][(t - 1) * 4 + b]) hp1[c][b * 128 + k2] = (unsigned)(v >> 32);
      }
      {  // h0(t)
        const unsigned long long* s0 =
            Hx0 + ((size_t)(t & 1) * 32 + pg * 2 + c) * 512;
        unsigned long long v;
        int sp = 0;
        for (;;) {
          v = __hip_atomic_load(s0 + idx, __ATOMIC_RELAXED, __HIP_MEMORY_SCOPE_AGENT);
          if ((unsigned)v == (unsigned)(t + 1)) break;
          if (++sp > (1 << 18)) break;
          __builtin_amdgcn_s_sleep(1);
        }
        const unsigned pay = (unsigned)(v >> 32);
        h0c[c][b * 128 + k2] = pay;
        if (opsA[c][t * 4 + b]) hp0[c][b * 128 + k2] = pay;
      }
    }
  };

  // ---- main loop: A/B chain-interleaved; polls backed by other chain ----
  for (int t = 0; t < TT; ++t) {
    dotsL0(0, t);
    __syncthreads();
    cell0(0, t);        // publish h0_A
    dotsL0(1, t);
    __syncthreads();
    cell0(1, t);        // publish h0_B
    mergeC(0, t);       // poll h0_A(t), h1_A(t-1)  [window: dotsL0_B+cell]
    __syncthreads();
    dotsL1(0);
    __syncthreads();
    cell1(0, t);        // out + publish h1_A
    mergeC(1, t);       // poll h0_B(t), h1_B(t-1)  [window: dotsL1_A+cell]
    __syncthreads();
    dotsL1(1);
    __syncthreads();
    cell1(1, t);        // out + publish h1_B
  }
}

// ---------------------------------------------------------------------------
extern "C" void kernel_launch(void* const* d_in, const int* in_sizes, int n_in,
                              void* d_out, int out_size, void* d_ws, size_t ws_size,
                              hipStream_t stream) {
  const float* x    = (const float*)d_in[0];
  const int*   ops  = (const int*)d_in[1];
  const float* W_ih = (const float*)d_in[2];
  const float* W_hh = (const float*)d_in[3];
  const float* b_ih = (const float*)d_in[4];
  const float* b_hh = (const float*)d_in[5];
  float* out = (float*)d_out;
  float* ws  = (float*)d_ws;

  pack_x<<<4096, 256, 0, stream>>>(x, ws);
  seq12<<<256, BLK, 0, stream>>>(W_ih, W_hh, b_ih, b_hh, ops, ws, out);
}